// Round 2
// baseline (155.937 us; speedup 1.0000x reference)
//
#include <hip/hip_runtime.h>

// PostProcessor3D: threshold(>0.9) + 5x5x5 stride-1 maxpool + strict-local-max
// mask on [64,512,512] fp32. Memory-bound separable stencil.
//
// Block: 32x32 threads = one (H,W) output tile, marching over a 16-deep D chunk.
// Per slice: stage thresholded 36x36 halo tile in LDS (prefetched into regs one
// slice ahead), W-max (5-tap) into 2nd LDS buffer, H-max into register, D-max
// via 5-entry register ring. Padding with 0 == reference's -inf padding because
// thresholded values are >= 0 and the in-bounds center is always in the window.
//
// R1 fix: LDS staging writes now use the SAME padded stride-37 layout as the
// readers (was flat 36x36 -> scrambled slice -> absmax 1.0).

#define THRESH 0.9f

constexpr int D = 64, H = 512, W = 512;
constexpr int TILE = 32;                 // (H,W) tile edge
constexpr int DCHUNK = 16;               // depth outputs per block
constexpr int HALO = 2;                  // radius
constexpr int LW = TILE + 2 * HALO;      // 36: staged tile edge
constexpr int RAW_STRIDE = LW + 1;       // 37: LDS pad (2-way max aliasing = free)
constexpr int WM_STRIDE = TILE + 1;      // 33

__global__ __launch_bounds__(1024)
void peak3d_kernel(const float* __restrict__ in, float* __restrict__ out) {
    __shared__ float raw[LW * RAW_STRIDE];    // 36 x 37 thresholded slice
    __shared__ float wmax[LW * WM_STRIDE];    // 36 x 33 W-direction 5-max

    const int tx = threadIdx.x;               // 0..31
    const int ty = threadIdx.y;               // 0..31
    const int tid = ty * 32 + tx;             // 0..1023

    const int w0 = blockIdx.x * TILE;
    const int h0 = blockIdx.y * TILE;
    const int d0 = blockIdx.z * DCHUNK;

    // Persistent load mapping: 36*36 = 1296 elements, <=2 per thread.
    const int i0 = tid;
    const int i1 = tid + 1024;
    const int r0 = i0 / LW, c0 = i0 % LW;
    const int r1 = i1 / LW, c1 = i1 % LW;
    const int lds0 = r0 * RAW_STRIDE + c0;    // padded LDS address (matches readers)
    const int lds1 = r1 * RAW_STRIDE + c1;
    const int gh0 = h0 + r0 - HALO, gw0 = w0 + c0 - HALO;
    const int gh1 = h0 + r1 - HALO, gw1 = w0 + c1 - HALO;
    const bool has1 = (i1 < LW * LW);
    const bool ib0 = (gh0 >= 0 && gh0 < H && gw0 >= 0 && gw0 < W);
    const bool ib1 = has1 && (gh1 >= 0 && gh1 < H && gw1 >= 0 && gw1 < W);
    const size_t off0 = ib0 ? ((size_t)gh0 * W + gw0) : 0;
    const size_t off1 = ib1 ? ((size_t)gh1 * W + gw1) : 0;

    float win[5], cen[5];
#pragma unroll
    for (int k = 0; k < 5; ++k) { win[k] = 0.f; cen[k] = 0.f; }

    auto loadSlice = [&](int dd, float& p0, float& p1) {
        p0 = 0.f; p1 = 0.f;
        if (dd >= 0 && dd < D) {
            size_t base = (size_t)dd * (H * W);
            if (ib0) { float v = in[base + off0]; p0 = (v > THRESH) ? v : 0.f; }
            if (ib1) { float v = in[base + off1]; p1 = (v > THRESH) ? v : 0.f; }
        }
    };

    float p0, p1;
    loadSlice(d0 - HALO, p0, p1);

    const int NS = DCHUNK + 2 * HALO;         // 20 slices
    for (int s = 0; s < NS; ++s) {
        const int ds = d0 - HALO + s;

        // commit prefetched slice to LDS (padded layout!)
        raw[lds0] = p0;
        if (has1) raw[lds1] = p1;
        // issue next slice's global loads (consumed next iteration -> latency
        // hidden behind this slice's compute + barriers)
        if (s + 1 < NS) loadSlice(ds + 1, p0, p1);
        __syncthreads();                      // raw ready

        const float tc = raw[(ty + HALO) * RAW_STRIDE + (tx + HALO)];

        // W-direction 5-max: 36 rows x 32 cols = 1152 items over 1024 threads
        {
            int it = tid;
#pragma unroll
            for (int pass = 0; pass < 2; ++pass) {
                if (it < LW * TILE) {
                    const int r = it >> 5, c = it & 31;
                    const float* rp = &raw[r * RAW_STRIDE + c];
                    float m = rp[0];
                    m = fmaxf(m, rp[1]); m = fmaxf(m, rp[2]);
                    m = fmaxf(m, rp[3]); m = fmaxf(m, rp[4]);
                    wmax[r * WM_STRIDE + c] = m;
                }
                it += 1024;
            }
        }
        __syncthreads();                      // wmax ready; all raw reads done

        // H-direction 5-max -> register ring
        const float* wp = &wmax[ty * WM_STRIDE + tx];
        float hv = wp[0];
        hv = fmaxf(hv, wp[1 * WM_STRIDE]);
        hv = fmaxf(hv, wp[2 * WM_STRIDE]);
        hv = fmaxf(hv, wp[3 * WM_STRIDE]);
        hv = fmaxf(hv, wp[4 * WM_STRIDE]);

        const int ri = ((ds % 5) + 5) % 5;
        win[ri] = hv;
        cen[ri] = tc;

        if (s >= 4) {
            const int dout = ds - HALO;       // d0 .. d0+15
            const float mp = fmaxf(fmaxf(fmaxf(win[0], win[1]),
                                         fmaxf(win[2], win[3])), win[4]);
            const int ci = ((dout % 5) + 5) % 5;
            const float tcc = cen[ci];
            const float res = (mp > 0.f && mp == tcc) ? mp : 0.f;
            out[(size_t)dout * (H * W) + (size_t)(h0 + ty) * W + (w0 + tx)] = res;
        }
        // NOTE: no 3rd barrier needed: next iteration's raw writes are ordered
        // after this iteration's raw reads by the wmax barrier above, and its
        // wmax writes are ordered after our wmax reads by its first barrier.
    }
}

extern "C" void kernel_launch(void* const* d_in, const int* in_sizes, int n_in,
                              void* d_out, int out_size, void* d_ws, size_t ws_size,
                              hipStream_t stream) {
    const float* in = (const float*)d_in[0];
    float* out = (float*)d_out;
    dim3 grid(W / TILE, H / TILE, D / DCHUNK);   // 16 x 16 x 4 = 1024 blocks
    dim3 block(32, 32, 1);
    hipLaunchKernelGGL(peak3d_kernel, grid, block, 0, stream, in, out);
}